// Round 10
// baseline (343.672 us; speedup 1.0000x reference)
//
#include <hip/hip_runtime.h>

// ---------------------------------------------------------------------------
// DeepCapsNet forward. conv2 = MFMA (bf16 hh+hl+lh split).
// R10: fit conv2 in 128 arch VGPRs (96 AGPRs acc + 128 arch = 224 <= 256):
//   - A staged via global_load_lds width=16 DMA (no VGPR round-trip);
//     h1 blocks padded to 11776 dw = 46 exact 1KB wave segments.
//   - fragment pass order hh -> lh -> hl cuts frag liveness 80 -> 64 regs.
// Block = 2 images x 256 co (512 thr, 8 waves 96x64), grid 256 = 1/CU.
// Workspace layout (dwords):
//   h1 : [0,        24117248)  ushort bf16, per (bi,chunk) block of 11776 dw:
//        hiE[4][190][8] | hiO[4][171][8] | loE | loO | pad 224 dw
//   Uws: [24117248, 24248320)  f32, [b][c=256]
//   Bt : [24248320, 24543232)  u32, [sidx][hi/lo][n=256][16dw]
//   w3T: [24543232, 24563968)  f32, [p=81][c=256]
//   Wr1: [24563968, 24629504)  f32, [j=8][i,k,l]
//   Wr2: [24629504, 24695040)  f32
//   Wr3: [24695040, 24736000)  f32
// total 98,944,000 bytes
// ---------------------------------------------------------------------------

typedef __attribute__((ext_vector_type(8))) short short8;   // 8 bf16
typedef __attribute__((ext_vector_type(4))) float f32x4;

__device__ __forceinline__ ushort f2bf(float x) {
    uint u = __float_as_uint(x);
    return (ushort)((u + 0x7FFFu + ((u >> 16) & 1u)) >> 16);
}
__device__ __forceinline__ void bfsplit(float x, ushort& h, ushort& l) {
    h = f2bf(x);
    float hf = __uint_as_float(((uint)h) << 16);
    l = f2bf(x - hf);
}
__device__ __forceinline__ void gload_lds16(const uint* g, uint* l) {
    __builtin_amdgcn_global_load_lds(
        (const __attribute__((address_space(1))) uint*)g,
        (__attribute__((address_space(3))) uint*)l, 16, 0, 0);
}

// ---------------- merged prep: Bt + w3T + Wr ------------------------------
__global__ __launch_bounds__(256) void k_prep(
    const float* __restrict__ w2, uint* __restrict__ Bt,
    const float* __restrict__ w3, float* __restrict__ w3T,
    const float* __restrict__ W1, const float* __restrict__ W2,
    const float* __restrict__ W3, float* __restrict__ Wr1,
    float* __restrict__ Wr2, float* __restrict__ Wr3) {
    __shared__ __align__(16) float wbuf[64 * 288];
    const int b = blockIdx.x, t = threadIdx.x;
    if (b < 144) {            // ---- Bt: [sidx][plane][n=256][16dw]
        const int sidx = b >> 2, coq = b & 3;
        const int chunk = sidx / 9, tap = sidx - chunk * 9;
        const int co0 = coq * 64;
        for (int idx = t; idx < 4608; idx += 256) {
            const int n = idx / 72, q = idx - n * 72;
            ((float4*)wbuf)[n * 72 + q] =
                *(const float4*)(w2 + (size_t)(co0 + n) * 1152 + chunk * 288 + q * 4);
        }
        __syncthreads();
        const int n = t & 63, dg = (t >> 6) * 4;
        const int nn = co0 + n;
        uint* dst = Bt + (size_t)sidx * 8192;
#pragma unroll
        for (int dd = 0; dd < 4; ++dd) {
            const int d = dg + dd;
            const float x = wbuf[n * 288 + (2 * d) * 9 + tap];
            const float y = wbuf[n * 288 + (2 * d + 1) * 9 + tap];
            ushort xh, xl, yh, yl;
            bfsplit(x, xh, xl);
            bfsplit(y, yh, yl);
            dst[nn * 16 + d]        = (uint)xh | ((uint)yh << 16);
            dst[4096 + nn * 16 + d] = (uint)xl | ((uint)yl << 16);
        }
    } else if (b < 225) {     // ---- w3T
        const int p = b - 144;
        w3T[p * 256 + t] = w3[t * 81 + p];
    } else {                  // ---- Wr: [j][(i,k,l)]
        const int bb = b - 225;
        const int layer = bb >> 5, blk = bb & 31;
        const float* src = layer == 0 ? W1 : (layer == 1 ? W2 : W3);
        float* dst = layer == 0 ? Wr1 : (layer == 1 ? Wr2 : Wr3);
        const int d_h = (layer == 2) ? 16 : 8;
        const int total = (layer == 2) ? 5120 : 8192;
        for (int idx = blk * 256 + t; idx < 8 * total; idx += 32 * 256) {
            const int j = idx / total, e = idx - j * total;
            const int ik = e / d_h, l = e - ik * d_h;
            dst[idx] = src[(ik * 8 + j) * d_h + l];
        }
    }
}

// ---------------- conv1: one block per image, bf16 plane output ------------
__global__ __launch_bounds__(256) void k_conv1(
    const float* __restrict__ x, const float* __restrict__ w,
    const float* __restrict__ bias, const float* __restrict__ g,
    const float* __restrict__ bb, const float* __restrict__ bm,
    const float* __restrict__ bv, ushort* __restrict__ h1) {
    __shared__ __align__(16) float xs[1521];
    __shared__ float wls[1152];
    __shared__ float2 scsh[128];
    const int b = blockIdx.x, t = threadIdx.x;
    const float* xb = x + (size_t)b * 1521;
    for (int i = t; i < 1521; i += 256) xs[i] = xb[i];
    for (int i = t; i < 1152; i += 256) wls[i] = w[i];
    if (t < 128) {
        const float inv = g[t] * rsqrtf(bv[t] + 1e-5f);
        scsh[t] = make_float2(inv, bias[t] * inv + bb[t] - bm[t] * inv);
    }
    __syncthreads();
    ushort* ib = h1 + (size_t)b * 94208;        // 4 chunks x 23552
#pragma unroll
    for (int f = 0; f < 2; ++f) {
        const int p = t + 256 * f;
        if (p >= 361) break;
        const int y = p / 19, xq = p - y * 19;
        const int base = y * 78 + xq * 2;
        const float x0 = xs[base],      x1 = xs[base + 1],  x2 = xs[base + 2];
        const float x3 = xs[base + 39], x4 = xs[base + 40], x5 = xs[base + 41];
        const float x6 = xs[base + 78], x7 = xs[base + 79], x8 = xs[base + 80];
        const int even = ((xq & 1) == 0);
        const int xi = xq >> 1;
        const int posE = y * 10 + xi, posO = y * 9 + xi;
#pragma unroll
        for (int oc = 0; oc < 16; ++oc) {
            short8 hs, ls;
#pragma unroll
            for (int j = 0; j < 8; ++j) {
                const int c = oc * 8 + j;
                const float* wp = wls + c * 9;
                float acc = x0 * wp[0] + x1 * wp[1] + x2 * wp[2] + x3 * wp[3] +
                            x4 * wp[4] + x5 * wp[5] + x6 * wp[6] + x7 * wp[7] + x8 * wp[8];
                const float2 ss = scsh[c];
                const float v = fmaxf(fmaf(acc, ss.x, ss.y), 0.0f);
                ushort hh, lw;
                bfsplit(v, hh, lw);
                hs[j] = (short)hh;
                ls[j] = (short)lw;
            }
            const int chunk = oc >> 2, o = oc & 3;
            ushort* cb = ib + chunk * 23552;
            if (even) {
                *(short8*)(cb + o * 1520 + posE * 8)         = hs;
                *(short8*)(cb + 11552 + o * 1520 + posE * 8) = ls;
            } else {
                *(short8*)(cb + 6080 + o * 1368 + posO * 8)  = hs;
                *(short8*)(cb + 17632 + o * 1368 + posO * 8) = ls;
            }
        }
    }
}

// ---------------- conv2: one block per image-pair, all 256 co --------------
// M = 2x96, N = 256, K = 4 chunks x 9 taps x 32ci. 8 waves, wave-tile 96x64.
// LDS: A 2x11776 dw + B dbuf 2x8192 dw = 159,744 B -> 1 block/CU, grid 256.
// A staged by global_load_lds DMA (no VGPRs); B via 16-reg relay into
// XOR-swizzled dbuf LDS. Frag pass order hh->lh->hl caps liveness at 64.
__global__ __launch_bounds__(512, 1) void k_conv2(
    const uint* __restrict__ h1u, const uint* __restrict__ Bt,
    const float* __restrict__ g,
    const float* __restrict__ bb, const float* __restrict__ bm,
    const float* __restrict__ bv, const float* __restrict__ bias,
    const float* __restrict__ w3T, float* __restrict__ Uws) {
    __shared__ __align__(16) uint lds[39936];   // A [0,23552)  B [23552,39936)
    const int t = threadIdx.x;
    const int lane = t & 63, wave = t >> 6;
    const int ln15 = lane & 15, lq = lane >> 4;
    const int img = wave >> 2, wn = (wave & 3) * 64;
    const int bi0 = blockIdx.x * 2;
    const int bi  = bi0 + img;                  // this wave's image

    int PE[6], PO[6];
#pragma unroll
    for (int i = 0; i < 6; ++i) {
        const int m = i * 16 + ln15;
        const int p = m < 81 ? m : 80;          // pad rows clamp
        const int oh = p / 9, ow = p - oh * 9;
        PE[i] = img * 11776 + lq * 760 + oh * 80 + ow * 4;
        PO[i] = img * 11776 + 3040 + lq * 684 + oh * 72 + ow * 4;
    }
    int BRD[4];                                 // B LDS read offsets (swizzled)
#pragma unroll
    for (int j = 0; j < 4; ++j) {
        const int n = wn + j * 16 + ln15;
        BRD[j] = n * 16 + ((lq ^ ((n >> 1) & 3)) << 2);
    }
    int BST[4];                                 // B LDS store offsets
#pragma unroll
    for (int k = 0; k < 4; ++k) {
        const int idx = t + k * 512;
        const int pl = idx >> 10, rem = idx & 1023;
        const int n = rem >> 2, q = idx & 3;
        BST[k] = pl * 4096 + n * 16 + ((q ^ ((n >> 1) & 3)) << 2);
    }

    f32x4 acc[6][4] = {};
    uint4 Bn[4];                                // next-tap B (register relay)
    {
        const uint4* sb = (const uint4*)Bt;     // s = 0
#pragma unroll
        for (int k = 0; k < 4; ++k) Bn[k] = sb[t + k * 512];
    }

    for (int c = 0; c < 4; ++c) {
        __syncthreads();                        // prior chunk's A readers done
        {   // ---- stage A(c), both images: direct HBM->LDS DMA, 1KB/segment
            const uint* gbase = h1u + (size_t)(bi0 * 4 + c) * 11776 + lane * 4;
#pragma unroll
            for (int q = 0; q < 12; ++q) {
                const int seg = wave + q * 8;
                if (seg < 92) {
                    const int im = seg >= 46;
                    const int off = seg - im * 46;
                    gload_lds16(gbase + im * 47104 + off * 256,
                                lds + im * 11776 + off * 256);
                }
            }
        }
#pragma unroll
        for (int tap = 0; tap < 9; ++tap) {
            const int s = c * 9 + tap;
            uint* ldsB = lds + 23552 + (s & 1) * 8192;
#pragma unroll
            for (int k = 0; k < 4; ++k) *(uint4*)(ldsB + BST[k]) = Bn[k];
            __syncthreads();   // drains vmcnt: A DMA (tap0) + B(s) visible
            if (s < 35) {                       // prefetch next-tap B
                const uint4* sb = (const uint4*)(Bt + (size_t)(s + 1) * 8192);
#pragma unroll
                for (int k = 0; k < 4; ++k) Bn[k] = sb[t + k * 512];
            }
            const int kh = tap / 3, kw = tap - kh * 3;
            const int odd = kw & 1;
            const int sE = kh * 40 + (kw >> 1) * 4;
            const int sO = kh * 36;
            short8 ah[6], bh[4];
#pragma unroll
            for (int i = 0; i < 6; ++i) {
                const int addr = odd ? (PO[i] + sO) : (PE[i] + sE);
                ah[i] = *reinterpret_cast<const short8*>(lds + addr);
            }
#pragma unroll
            for (int j = 0; j < 4; ++j)
                bh[j] = *reinterpret_cast<const short8*>(ldsB + BRD[j]);
            // ---- pass 1: hh
#pragma unroll
            for (int i = 0; i < 6; ++i)
#pragma unroll
                for (int j = 0; j < 4; ++j)
                    acc[i][j] = __builtin_amdgcn_mfma_f32_16x16x32_bf16(ah[i], bh[j], acc[i][j], 0, 0, 0);
            // ---- pass 2: lh (al transient; bh dies after)
            {
                short8 al[6];
#pragma unroll
                for (int i = 0; i < 6; ++i) {
                    const int addr = odd ? (PO[i] + sO) : (PE[i] + sE);
                    al[i] = *reinterpret_cast<const short8*>(lds + addr + 5776);
                }
#pragma unroll
                for (int i = 0; i < 6; ++i)
#pragma unroll
                    for (int j = 0; j < 4; ++j)
                        acc[i][j] = __builtin_amdgcn_mfma_f32_16x16x32_bf16(al[i], bh[j], acc[i][j], 0, 0, 0);
            }
            // ---- pass 3: hl (bl transient)
            {
                short8 bl[4];
#pragma unroll
                for (int j = 0; j < 4; ++j)
                    bl[j] = *reinterpret_cast<const short8*>(ldsB + 4096 + BRD[j]);
#pragma unroll
                for (int i = 0; i < 6; ++i)
#pragma unroll
                    for (int j = 0; j < 4; ++j)
                        acc[i][j] = __builtin_amdgcn_mfma_f32_16x16x32_bf16(ah[i], bl[j], acc[i][j], 0, 0, 0);
            }
        }
    }

    // ---- epilogue: bn + relu + fused conv3, pure in-wave reduction --------
    float scj[4], shj[4];
#pragma unroll
    for (int j = 0; j < 4; ++j) {
        const int co = wn + j * 16 + ln15;
        const float inv = g[co] * rsqrtf(bv[co] + 1e-5f);
        scj[j] = inv;
        shj[j] = bias[co] * inv + bb[co] - bm[co] * inv;
    }
    float usum[4] = {0.f, 0.f, 0.f, 0.f};
#pragma unroll
    for (int i = 0; i < 6; ++i)
#pragma unroll
        for (int r = 0; r < 4; ++r) {
            const int m = i * 16 + lq * 4 + r;
            if (m < 81) {
                const float* wrow = w3T + m * 256;
#pragma unroll
                for (int j = 0; j < 4; ++j) {
                    const int co = wn + j * 16 + ln15;
                    const float v = fmaxf(fmaf(acc[i][j][r], scj[j], shj[j]), 0.0f);
                    usum[j] = fmaf(v, wrow[co], usum[j]);
                }
            }
        }
#pragma unroll
    for (int j = 0; j < 4; ++j) {               // reduce over lq (rows)
        usum[j] += __shfl_xor(usum[j], 16);
        usum[j] += __shfl_xor(usum[j], 32);
    }
    if (lq == 0) {
#pragma unroll
        for (int j = 0; j < 4; ++j)
            Uws[(size_t)bi * 256 + wn + j * 16 + ln15] = usum[j];
    }
}

// ---------------- fused squash + 3x fccaps ---------------------------------
__device__ __forceinline__ void fccaps_block(
    const int n_l, const int n_h, const int d_h, const float* __restrict__ Wr,
    float* U, float* Uh, float* Sv, float* Av, float* Cv, float* coefs,
    float* outU, const int t) {
    const int nkd = n_h * d_h;
    const int total = n_l * nkd;
    __syncthreads();
    for (int e = t; e < total; e += 256) {
        const int i = e / nkd;
        const float* up = U + i * 8;
        float acc = 0.0f;
#pragma unroll
        for (int j = 0; j < 8; ++j) acc += up[j] * Wr[j * total + e];
        Uh[e] = acc;
    }
    __syncthreads();
    for (int e = t; e < nkd; e += 256) {
        float acc = 0.0f;
        for (int i = 0; i < n_l; ++i) acc += Uh[i * nkd + e];
        Sv[e] = acc;
    }
    __syncthreads();
    for (int e = t; e < n_l * n_h; e += 256) {
        const int h = e / n_h, k = e - h * n_h;
        float acc = 0.0f;
        for (int l = 0; l < d_h; ++l)
            acc += Uh[h * nkd + k * d_h + l] * Sv[k * d_h + l];
        Av[e] = acc;
    }
    __syncthreads();
    {   // parallel softmax over k: 8 lanes per row h
        const int h = t >> 3, sub = t & 7;
        const float invs = 1.0f / 2.8284271247461903f;
        float mx = -1e30f;
        for (int k = sub; k < n_h; k += 8) mx = fmaxf(mx, Av[h * n_h + k]);
        mx = fmaxf(mx, __shfl_xor(mx, 1));
        mx = fmaxf(mx, __shfl_xor(mx, 2));
        mx = fmaxf(mx, __shfl_xor(mx, 4));
        float sum = 0.0f;
        for (int k = sub; k < n_h; k += 8) {
            const float ev = expf((Av[h * n_h + k] - mx) * invs);
            Cv[h * n_h + k] = ev;
            sum += ev;
        }
        sum += __shfl_xor(sum, 1);
        sum += __shfl_xor(sum, 2);
        sum += __shfl_xor(sum, 4);
        const float r = 1.0f / sum;
        for (int k = sub; k < n_h; k += 8) Cv[h * n_h + k] *= r;
    }
    __syncthreads();
    for (int e = t; e < nkd; e += 256) {
        const int k = e / d_h;
        float acc = 0.0f;
        for (int i = 0; i < n_l; ++i) acc += Uh[i * nkd + e] * Cv[i * n_h + k];
        Sv[e] = acc;
    }
    __syncthreads();
    if (t < n_h) {
        float ssq = 0.0f;
        for (int l = 0; l < d_h; ++l) { const float uv = Sv[t * d_h + l]; ssq += uv * uv; }
        const float n = sqrtf(ssq);
        coefs[t] = (1.0f - 1.0f / (expf(n) + 1e-20f)) / (n + 1e-20f);
    }
    __syncthreads();
    for (int e = t; e < nkd; e += 256) outU[e] = Sv[e] * coefs[e / d_h];
}

__global__ __launch_bounds__(256) void k_caps(
    const float* __restrict__ Uws, const float* __restrict__ b3,
    const float* __restrict__ Wr1, const float* __restrict__ Wr2,
    const float* __restrict__ Wr3, float* __restrict__ out) {
    __shared__ float U[256];
    __shared__ float Uh[8192];
    __shared__ float Sv[256];
    __shared__ float Av[1024];
    __shared__ float Cv[1024];
    __shared__ float coefs[32];
    const int b = blockIdx.x, t = threadIdx.x;
    U[t] = Uws[(size_t)b * 256 + t] + b3[t];
    __syncthreads();
    if (t < 32) {
        float ssq = 0.0f;
        for (int j = 0; j < 8; ++j) { const float uv = U[t * 8 + j]; ssq += uv * uv; }
        const float n = sqrtf(ssq);
        coefs[t] = (1.0f - 1.0f / (expf(n) + 1e-20f)) / (n + 1e-20f);
    }
    __syncthreads();
    U[t] *= coefs[t >> 3];
    fccaps_block(32, 32,  8, Wr1, U, Uh, Sv, Av, Cv, coefs, U, t);
    fccaps_block(32, 32,  8, Wr2, U, Uh, Sv, Av, Cv, coefs, U, t);
    fccaps_block(32, 10, 16, Wr3, U, Uh, Sv, Av, Cv, coefs, out + (size_t)b * 160, t);
}

// ---------------------------------------------------------------------------
extern "C" void kernel_launch(void* const* d_in, const int* in_sizes, int n_in,
                              void* d_out, int out_size, void* d_ws, size_t ws_size,
                              hipStream_t stream) {
    const float* x    = (const float*)d_in[0];
    const float* c1w  = (const float*)d_in[1];
    const float* c1b  = (const float*)d_in[2];
    const float* bn1g = (const float*)d_in[3];
    const float* bn1b = (const float*)d_in[4];
    const float* bn1m = (const float*)d_in[5];
    const float* bn1v = (const float*)d_in[6];
    const float* c2w  = (const float*)d_in[7];
    const float* c2b  = (const float*)d_in[8];
    const float* bn2g = (const float*)d_in[9];
    const float* bn2b = (const float*)d_in[10];
    const float* bn2m = (const float*)d_in[11];
    const float* bn2v = (const float*)d_in[12];
    const float* c3w  = (const float*)d_in[13];
    const float* c3b  = (const float*)d_in[14];
    const float* W1   = (const float*)d_in[15];
    const float* W2   = (const float*)d_in[16];
    const float* W3   = (const float*)d_in[17];
    float* out = (float*)d_out;
    uint*  wsu = (uint*)d_ws;
    float* wsf = (float*)d_ws;

    ushort* h1  = (ushort*)wsu;          // 24,117,248 dw as padded bf16 planes
    float*  Uws = wsf + 24117248;        //    131,072 dw
    uint*   Bt  = wsu + 24248320;        //    294,912 dw
    float*  w3T = wsf + 24543232;        //     20,736 dw
    float*  Wr1 = wsf + 24563968;        //     65,536 dw
    float*  Wr2 = wsf + 24629504;        //     65,536 dw
    float*  Wr3 = wsf + 24695040;        //     40,960 dw

    k_prep<<<dim3(321), 256, 0, stream>>>(c2w, Bt, c3w, w3T, W1, W2, W3,
                                          Wr1, Wr2, Wr3);
    k_conv1<<<dim3(512), 256, 0, stream>>>(x, c1w, c1b, bn1g, bn1b, bn1m, bn1v, h1);
    k_conv2<<<dim3(256), 512, 0, stream>>>((const uint*)h1, Bt, bn2g, bn2b, bn2m, bn2v,
                                           c2b, w3T, Uws);
    k_caps<<<dim3(512), 256, 0, stream>>>(Uws, c3b, Wr1, Wr2, Wr3, out);
}

// Round 11
// 227.977 us; speedup vs baseline: 1.5075x; 1.5075x over previous
//
#include <hip/hip_runtime.h>

// ---------------------------------------------------------------------------
// DeepCapsNet forward. conv2 = MFMA (bf16 hh+hl+lh split), r7 structure
// (93 us, 84 VGPR, 3 blocks/CU — best measured; R8-R10 big-block direction
// abandoned: 96 AGPR acc + 128 arch VGPR cap forces spill, 3x confirmed).
// R11: conv1 rewritten — weights in registers per (octet,posgroup) thread,
// kills the 2304 scalar-LDS-reads/thread storm (131 us -> write-bound).
// Workspace layout (dwords):
//   h1 : [0,        23658496)  ushort bf16, per (bi,chunk) block of 11552 dw:
//        hiE[4][190][8] | hiO[4][171][8] | loE | loO
//   Uws: [23658496, 23789568)  f32, [b][c=256]
//   Bt : [23789568, 24084480)  u32, [sidx][cot][hi/lo][n=128][16dw]
//   w3T: [24084480, 24105216)  f32, [p=81][c=256]
//   Wr1: [24105216, 24170752)  f32, [j=8][i,k,l]
//   Wr2: [24170752, 24236288)  f32
//   Wr3: [24236288, 24277248)  f32
// total 97,108,992 bytes
// ---------------------------------------------------------------------------

typedef __attribute__((ext_vector_type(8))) short short8;   // 8 bf16
typedef __attribute__((ext_vector_type(4))) float f32x4;

__device__ __forceinline__ ushort f2bf(float x) {
    uint u = __float_as_uint(x);
    return (ushort)((u + 0x7FFFu + ((u >> 16) & 1u)) >> 16);
}
__device__ __forceinline__ void bfsplit(float x, ushort& h, ushort& l) {
    h = f2bf(x);
    float hf = __uint_as_float(((uint)h) << 16);
    l = f2bf(x - hf);
}

// ---------------- merged prep: Bt + w3T + Wr ------------------------------
__global__ __launch_bounds__(256) void k_prep(
    const float* __restrict__ w2, uint* __restrict__ Bt,
    const float* __restrict__ w3, float* __restrict__ w3T,
    const float* __restrict__ W1, const float* __restrict__ W2,
    const float* __restrict__ W3, float* __restrict__ Wr1,
    float* __restrict__ Wr2, float* __restrict__ Wr3) {
    __shared__ __align__(16) float wbuf[64 * 288];
    const int b = blockIdx.x, t = threadIdx.x;
    if (b < 144) {            // ---- Bt: [sidx][cot][hi/lo][n=128][16dw]
        const int sidx = b >> 2, coq = b & 3;
        const int chunk = sidx / 9, tap = sidx - chunk * 9;
        const int co0 = coq * 64;
        for (int idx = t; idx < 4608; idx += 256) {
            const int n = idx / 72, q = idx - n * 72;
            ((float4*)wbuf)[n * 72 + q] =
                *(const float4*)(w2 + (size_t)(co0 + n) * 1152 + chunk * 288 + q * 4);
        }
        __syncthreads();
        const int n = t & 63, dg = (t >> 6) * 4;
        const int cot = coq >> 1, nn = ((coq & 1) * 64) + n;
        uint* dst = Bt + (size_t)(sidx * 2 + cot) * 4096;
#pragma unroll
        for (int dd = 0; dd < 4; ++dd) {
            const int d = dg + dd;
            const float x = wbuf[n * 288 + (2 * d) * 9 + tap];
            const float y = wbuf[n * 288 + (2 * d + 1) * 9 + tap];
            ushort xh, xl, yh, yl;
            bfsplit(x, xh, xl);
            bfsplit(y, yl == yl ? yh : yh, yl);   // (no-op guard removed below)
            bfsplit(y, yh, yl);
            dst[nn * 16 + d]        = (uint)xh | ((uint)yh << 16);
            dst[2048 + nn * 16 + d] = (uint)xl | ((uint)yl << 16);
        }
    } else if (b < 225) {     // ---- w3T
        const int p = b - 144;
        w3T[p * 256 + t] = w3[t * 81 + p];
    } else {                  // ---- Wr: [j][(i,k,l)]
        const int bb = b - 225;
        const int layer = bb >> 5, blk = bb & 31;
        const float* src = layer == 0 ? W1 : (layer == 1 ? W2 : W3);
        float* dst = layer == 0 ? Wr1 : (layer == 1 ? Wr2 : Wr3);
        const int d_h = (layer == 2) ? 16 : 8;
        const int total = (layer == 2) ? 5120 : 8192;
        for (int idx = blk * 256 + t; idx < 8 * total; idx += 32 * 256) {
            const int j = idx / total, e = idx - j * total;
            const int ik = e / d_h, l = e - ik * d_h;
            dst[idx] = src[(ik * 8 + j) * d_h + l];
        }
    }
}

// ---------------- conv1: weights-in-registers, one block per image ---------
// thread = (octet o = t&15, position-group pg = t>>4). Each thread: 72 weight
// floats + 8 bn pairs in regs, sweeps positions p = pg, pg+16, ... (<=23).
// LDS reads: 9 xs per position (4-lane broadcast), vs 2304 scalar before.
__global__ __launch_bounds__(256) void k_conv1(
    const float* __restrict__ x, const float* __restrict__ w,
    const float* __restrict__ bias, const float* __restrict__ g,
    const float* __restrict__ bb, const float* __restrict__ bm,
    const float* __restrict__ bv, ushort* __restrict__ h1) {
    __shared__ __align__(16) float xs[1521];
    __shared__ float wls[1152];
    __shared__ float2 scsh[128];
    const int b = blockIdx.x, t = threadIdx.x;
    const float* xb = x + (size_t)b * 1521;
    for (int i = t; i < 1521; i += 256) xs[i] = xb[i];
    for (int i = t; i < 1152; i += 256) wls[i] = w[i];
    if (t < 128) {
        const float inv = g[t] * rsqrtf(bv[t] + 1e-5f);
        scsh[t] = make_float2(inv, bias[t] * inv + bb[t] - bm[t] * inv);
    }
    __syncthreads();
    const int o = t & 15, pg = t >> 4;
    float wr[8][9];
#pragma unroll
    for (int j = 0; j < 8; ++j)
#pragma unroll
        for (int k = 0; k < 9; ++k) wr[j][k] = wls[(o * 8 + j) * 9 + k];
    float2 ss[8];
#pragma unroll
    for (int j = 0; j < 8; ++j) ss[j] = scsh[o * 8 + j];
    const int chunk = o >> 2, ol = o & 3;
    ushort* cb = h1 + (size_t)b * 92416 + chunk * 23104;
    for (int p = pg; p < 361; p += 16) {
        const int y = p / 19, xq = p - y * 19;
        const int base = y * 78 + xq * 2;
        const float x0 = xs[base],      x1 = xs[base + 1],  x2 = xs[base + 2];
        const float x3 = xs[base + 39], x4 = xs[base + 40], x5 = xs[base + 41];
        const float x6 = xs[base + 78], x7 = xs[base + 79], x8 = xs[base + 80];
        short8 hs, ls;
#pragma unroll
        for (int j = 0; j < 8; ++j) {
            const float acc = x0 * wr[j][0] + x1 * wr[j][1] + x2 * wr[j][2] +
                              x3 * wr[j][3] + x4 * wr[j][4] + x5 * wr[j][5] +
                              x6 * wr[j][6] + x7 * wr[j][7] + x8 * wr[j][8];
            const float v = fmaxf(fmaf(acc, ss[j].x, ss[j].y), 0.0f);
            ushort hh, lw;
            bfsplit(v, hh, lw);
            hs[j] = (short)hh;
            ls[j] = (short)lw;
        }
        if ((xq & 1) == 0) {
            const int pos = y * 10 + (xq >> 1);
            *(short8*)(cb + ol * 1520 + pos * 8)         = hs;
            *(short8*)(cb + 11552 + ol * 1520 + pos * 8) = ls;
        } else {
            const int pos = y * 9 + (xq >> 1);
            *(short8*)(cb + 6080 + ol * 1368 + pos * 8)  = hs;
            *(short8*)(cb + 17632 + ol * 1368 + pos * 8) = ls;
        }
    }
}

// ---------------- conv2: r7 structure (93 us verified) ---------------------
// One block per (image, co-half). M=81 (pad 96), N=128, K = 4x9x32.
// 4 waves, wave 48x64. LDS = one (bi,chunk) h1 block (46.2 KB) -> 3 blocks/CU.
// B fragments prefetched one tap ahead in regs; conv3 fused in epilogue.
__global__ __launch_bounds__(256, 3) void k_conv2(
    const uint* __restrict__ h1u, const uint* __restrict__ Bt,
    const float* __restrict__ g,
    const float* __restrict__ bb, const float* __restrict__ bm,
    const float* __restrict__ bv, const float* __restrict__ bias,
    const float* __restrict__ w3T, float* __restrict__ Uws) {
    __shared__ __align__(16) uint raw[11552];
    __shared__ float ured[128];
    const int t = threadIdx.x;
    const int lane = t & 63, wave = t >> 6;
    const int ln15 = lane & 15, lq = lane >> 4;
    const int wm = (wave >> 1) * 48, wn = (wave & 1) * 64;
    const int gg = blockIdx.x;
    const int bi  = ((gg >> 4) << 3) | (gg & 7);   // XCD-pair swizzle
    const int cot = (gg >> 3) & 1;
    const int co0 = cot * 128;

    int PE[3], PO[3];
#pragma unroll
    for (int i = 0; i < 3; ++i) {
        const int m = wm + i * 16 + ln15;
        const int p = m < 81 ? m : 80;       // pad rows clamp
        const int oh = p / 9, ow = p - oh * 9;
        PE[i] = lq * 760 + oh * 80 + ow * 4;
        PO[i] = 3040 + lq * 684 + oh * 72 + ow * 4;
    }
    int BRDg[4];
#pragma unroll
    for (int j = 0; j < 4; ++j) {
        const int n = wn + j * 16 + ln15;
        BRDg[j] = n * 16 + lq * 4;
    }

    f32x4 acc[3][4] = {};
    uint4 Bn[8];
    {   // prologue: prefetch s = 0
        const uint* bp = Bt + (size_t)cot * 4096;
#pragma unroll
        for (int j = 0; j < 4; ++j) {
            Bn[j]     = *(const uint4*)(bp + BRDg[j]);
            Bn[4 + j] = *(const uint4*)(bp + 2048 + BRDg[j]);
        }
    }

#pragma unroll
    for (int c = 0; c < 4; ++c) {
        __syncthreads();
        {   // stage the (bi,chunk) block: clustered loads then stores
            const uint4* src = (const uint4*)(h1u + (size_t)(bi * 4 + c) * 11552);
            uint4* dst = (uint4*)raw;
            uint4 tmp[11];
#pragma unroll
            for (int k = 0; k < 11; ++k) tmp[k] = src[t + k * 256];
            const bool extra = (t < 72);
            uint4 te;
            if (extra) te = src[t + 11 * 256];
#pragma unroll
            for (int k = 0; k < 11; ++k) dst[t + k * 256] = tmp[k];
            if (extra) dst[t + 11 * 256] = te;
        }
        __syncthreads();
        short8 a_h[3];
#pragma unroll
        for (int i = 0; i < 3; ++i)
            a_h[i] = *reinterpret_cast<const short8*>(raw + PE[i]);
#pragma unroll
        for (int tap = 0; tap < 9; ++tap) {
            const int s = c * 9 + tap;
            uint4 Bc[8];
#pragma unroll
            for (int q = 0; q < 8; ++q) Bc[q] = Bn[q];
            if (s < 35) {
                const uint* bp = Bt + (size_t)((s + 1) * 2 + cot) * 4096;
#pragma unroll
                for (int j = 0; j < 4; ++j) {
                    Bn[j]     = *(const uint4*)(bp + BRDg[j]);
                    Bn[4 + j] = *(const uint4*)(bp + 2048 + BRDg[j]);
                }
            }
            const int kh = tap / 3, kw = tap - kh * 3;
            const int odd = kw & 1;
            const int sE = kh * 40 + (kw >> 1) * 4;
            const int sO = kh * 36;
            short8 a_l[3];
#pragma unroll
            for (int i = 0; i < 3; ++i) {
                const int addr = odd ? (PO[i] + sO) : (PE[i] + sE);
                a_l[i] = *reinterpret_cast<const short8*>(raw + addr + 5776);
            }
            short8 a_hn[3];
            if (tap < 8) {
                const int tap2 = tap + 1;
                const int kh2 = tap2 / 3, kw2 = tap2 - kh2 * 3;
                const int odd2 = kw2 & 1;
                const int sE2 = kh2 * 40 + (kw2 >> 1) * 4;
                const int sO2 = kh2 * 36;
#pragma unroll
                for (int i = 0; i < 3; ++i) {
                    const int addr2 = odd2 ? (PO[i] + sO2) : (PE[i] + sE2);
                    a_hn[i] = *reinterpret_cast<const short8*>(raw + addr2);
                }
            }
            short8 bh[4], bl[4];
#pragma unroll
            for (int j = 0; j < 4; ++j) {
                bh[j] = __builtin_bit_cast(short8, Bc[j]);
                bl[j] = __builtin_bit_cast(short8, Bc[4 + j]);
            }
#pragma unroll
            for (int i = 0; i < 3; ++i)
#pragma unroll
                for (int j = 0; j < 4; ++j)
                    acc[i][j] = __builtin_amdgcn_mfma_f32_16x16x32_bf16(a_h[i], bh[j], acc[i][j], 0, 0, 0);
#pragma unroll
            for (int i = 0; i < 3; ++i)
#pragma unroll
                for (int j = 0; j < 4; ++j)
                    acc[i][j] = __builtin_amdgcn_mfma_f32_16x16x32_bf16(a_h[i], bl[j], acc[i][j], 0, 0, 0);
#pragma unroll
            for (int i = 0; i < 3; ++i)
#pragma unroll
                for (int j = 0; j < 4; ++j)
                    acc[i][j] = __builtin_amdgcn_mfma_f32_16x16x32_bf16(a_l[i], bh[j], acc[i][j], 0, 0, 0);
            if (tap < 8) {
#pragma unroll
                for (int i = 0; i < 3; ++i) a_h[i] = a_hn[i];
            }
        }
    }

    // ---- epilogue: bn + relu + fused depthwise conv3 reduction ------------
    float scj[4], shj[4];
#pragma unroll
    for (int j = 0; j < 4; ++j) {
        const int co = co0 + wn + j * 16 + ln15;
        const float inv = g[co] * rsqrtf(bv[co] + 1e-5f);
        scj[j] = inv;
        shj[j] = bias[co] * inv + bb[co] - bm[co] * inv;
    }
    float usum[4] = {0.f, 0.f, 0.f, 0.f};
#pragma unroll
    for (int i = 0; i < 3; ++i)
#pragma unroll
        for (int r = 0; r < 4; ++r) {
            const int m = wm + i * 16 + lq * 4 + r;
            if (m < 81) {
                const float* wrow = w3T + m * 256 + co0;
#pragma unroll
                for (int j = 0; j < 4; ++j) {
                    const int col = wn + j * 16 + ln15;
                    const float v = fmaxf(fmaf(acc[i][j][r], scj[j], shj[j]), 0.0f);
                    usum[j] = fmaf(v, wrow[col], usum[j]);
                }
            }
        }
#pragma unroll
    for (int j = 0; j < 4; ++j) {
        usum[j] += __shfl_xor(usum[j], 16);
        usum[j] += __shfl_xor(usum[j], 32);
    }
    if (lq == 0 && wm == 0) {
#pragma unroll
        for (int j = 0; j < 4; ++j) ured[(wn >> 6) * 64 + j * 16 + ln15] = usum[j];
    }
    __syncthreads();
    if (lq == 0 && wm == 48) {
#pragma unroll
        for (int j = 0; j < 4; ++j) {
            const int col = wn + j * 16 + ln15;
            Uws[(size_t)bi * 256 + co0 + col] =
                usum[j] + ured[(wn >> 6) * 64 + j * 16 + ln15];
        }
    }
}

// ---------------- fused squash + 3x fccaps ---------------------------------
__device__ __forceinline__ void fccaps_block(
    const int n_l, const int n_h, const int d_h, const float* __restrict__ Wr,
    float* U, float* Uh, float* Sv, float* Av, float* Cv, float* coefs,
    float* outU, const int t) {
    const int nkd = n_h * d_h;
    const int total = n_l * nkd;
    __syncthreads();
    for (int e = t; e < total; e += 256) {
        const int i = e / nkd;
        const float* up = U + i * 8;
        float acc = 0.0f;
#pragma unroll
        for (int j = 0; j < 8; ++j) acc += up[j] * Wr[j * total + e];
        Uh[e] = acc;
    }
    __syncthreads();
    for (int e = t; e < nkd; e += 256) {
        float acc = 0.0f;
        for (int i = 0; i < n_l; ++i) acc += Uh[i * nkd + e];
        Sv[e] = acc;
    }
    __syncthreads();
    for (int e = t; e < n_l * n_h; e += 256) {
        const int h = e / n_h, k = e - h * n_h;
        float acc = 0.0f;
        for (int l = 0; l < d_h; ++l)
            acc += Uh[h * nkd + k * d_h + l] * Sv[k * d_h + l];
        Av[e] = acc;
    }
    __syncthreads();
    {   // parallel softmax over k: 8 lanes per row h
        const int h = t >> 3, sub = t & 7;
        const float invs = 1.0f / 2.8284271247461903f;
        float mx = -1e30f;
        for (int k = sub; k < n_h; k += 8) mx = fmaxf(mx, Av[h * n_h + k]);
        mx = fmaxf(mx, __shfl_xor(mx, 1));
        mx = fmaxf(mx, __shfl_xor(mx, 2));
        mx = fmaxf(mx, __shfl_xor(mx, 4));
        float sum = 0.0f;
        for (int k = sub; k < n_h; k += 8) {
            const float ev = expf((Av[h * n_h + k] - mx) * invs);
            Cv[h * n_h + k] = ev;
            sum += ev;
        }
        sum += __shfl_xor(sum, 1);
        sum += __shfl_xor(sum, 2);
        sum += __shfl_xor(sum, 4);
        const float r = 1.0f / sum;
        for (int k = sub; k < n_h; k += 8) Cv[h * n_h + k] *= r;
    }
    __syncthreads();
    for (int e = t; e < nkd; e += 256) {
        const int k = e / d_h;
        float acc = 0.0f;
        for (int i = 0; i < n_l; ++i) acc += Uh[i * nkd + e] * Cv[i * n_h + k];
        Sv[e] = acc;
    }
    __syncthreads();
    if (t < n_h) {
        float ssq = 0.0f;
        for (int l = 0; l < d_h; ++l) { const float uv = Sv[t * d_h + l]; ssq += uv * uv; }
        const float n = sqrtf(ssq);
        coefs[t] = (1.0f - 1.0f / (expf(n) + 1e-20f)) / (n + 1e-20f);
    }
    __syncthreads();
    for (int e = t; e < nkd; e += 256) outU[e] = Sv[e] * coefs[e / d_h];
}

__global__ __launch_bounds__(256) void k_caps(
    const float* __restrict__ Uws, const float* __restrict__ b3,
    const float* __restrict__ Wr1, const float* __restrict__ Wr2,
    const float* __restrict__ Wr3, float* __restrict__ out) {
    __shared__ float U[256];
    __shared__ float Uh[8192];
    __shared__ float Sv[256];
    __shared__ float Av[1024];
    __shared__ float Cv[1024];
    __shared__ float coefs[32];
    const int b = blockIdx.x, t = threadIdx.x;
    U[t] = Uws[(size_t)b * 256 + t] + b3[t];
    __syncthreads();
    if (t < 32) {
        float ssq = 0.0f;
        for (int j = 0; j < 8; ++j) { const float uv = U[t * 8 + j]; ssq += uv * uv; }
        const float n = sqrtf(ssq);
        coefs[t] = (1.0f - 1.0f / (expf(n) + 1e-20f)) / (n + 1e-20f);
    }
    __syncthreads();
    U[t] *= coefs[t >> 3];
    fccaps_block(32, 32,  8, Wr1, U, Uh, Sv, Av, Cv, coefs, U, t);
    fccaps_block(32, 32,  8, Wr2, U, Uh, Sv, Av, Cv, coefs, U, t);
    fccaps_block(32, 10, 16, Wr3, U, Uh, Sv, Av, Cv, coefs, out + (size_t)b * 160, t);
}

// ---------------------------------------------------------------------------
extern "C" void kernel_launch(void* const* d_in, const int* in_sizes, int n_in,
                              void* d_out, int out_size, void* d_ws, size_t ws_size,
                              hipStream_t stream) {
    const float* x    = (const float*)d_in[0];
    const float* c1w  = (const float*)d_in[1];
    const float* c1b  = (const float*)d_in[2];
    const float* bn1g = (const float*)d_in[3];
    const float* bn1b = (const float*)d_in[4];
    const float* bn1m = (const float*)d_in[5];
    const float* bn1v = (const float*)d_in[6];
    const float* c2w  = (const float*)d_in[7];
    const float* c2b  = (const float*)d_in[8];
    const float* bn2g = (const float*)d_in[9];
    const float* bn2b = (const float*)d_in[10];
    const float* bn2m = (const float*)d_in[11];
    const float* bn2v = (const float*)d_in[12];
    const float* c3w  = (const float*)d_in[13];
    const float* c3b  = (const float*)d_in[14];
    const float* W1   = (const float*)d_in[15];
    const float* W2   = (const float*)d_in[16];
    const float* W3   = (const float*)d_in[17];
    float* out = (float*)d_out;
    uint*  wsu = (uint*)d_ws;
    float* wsf = (float*)d_ws;

    ushort* h1  = (ushort*)wsu;          // 23,658,496 dw as bf16 planes
    float*  Uws = wsf + 23658496;        //    131,072 dw
    uint*   Bt  = wsu + 23789568;        //    294,912 dw
    float*  w3T = wsf + 24084480;        //     20,736 dw
    float*  Wr1 = wsf + 24105216;        //     65,536 dw
    float*  Wr2 = wsf + 24170752;        //     65,536 dw
    float*  Wr3 = wsf + 24236288;        //     40,960 dw

    k_prep<<<dim3(321), 256, 0, stream>>>(c2w, Bt, c3w, w3T, W1, W2, W3,
                                          Wr1, Wr2, Wr3);
    k_conv1<<<dim3(512), 256, 0, stream>>>(x, c1w, c1b, bn1g, bn1b, bn1m, bn1v, h1);
    k_conv2<<<dim3(1024), 256, 0, stream>>>((const uint*)h1, Bt, bn2g, bn2b, bn2m, bn2v,
                                            c2b, w3T, Uws);
    k_caps<<<dim3(512), 256, 0, stream>>>(Uws, c3b, Wr1, Wr2, Wr3, out);
}